// Round 3
// baseline (427.757 us; speedup 1.0000x reference)
//
#include <hip/hip_runtime.h>

// Problem constants: B=2, S=2048, D=2048, H=16, DH=128
#define B_  2
#define S_  2048
#define D_  2048
#define H_  16
#define DH_ 128
#define NQKV 6144              // Q|K|V concatenated column dim

typedef __bf16 bf16;
typedef __bf16 bf16x2 __attribute__((ext_vector_type(2)));
typedef __bf16 bf16x4 __attribute__((ext_vector_type(4)));
typedef __bf16 bf16x8 __attribute__((ext_vector_type(8)));
typedef float  f32x4  __attribute__((ext_vector_type(4)));

// 2^x and log2(x) via the raw ISA ops (v_exp_f32 / v_log_f32).
#define EXP2F(x) __builtin_amdgcn_exp2f(x)
#define LOG2F(x) __builtin_amdgcn_logf(x)

// DH^-0.5 * log2(e): fold softmax scale AND the exp->exp2 conversion into Q.
static constexpr float kQScale = 0.08838834764831845f * 1.4426950408889634f;

__device__ __forceinline__ void async16(const void* g, void* l) {
  __builtin_amdgcn_global_load_lds(
      (const __attribute__((address_space(1))) void*)g,
      (__attribute__((address_space(3))) void*)l, 16, 0, 0);
}

// ---------------------------------------------------------------------------
// Single fp32 -> bf16 conversion kernel for all 5 tensors (block-uniform
// region select; merging 5 dispatches -> 1 to cut launch overhead).
// Regions (blocks of 1024 elems): x:8192 | Wq:4096 | Wk:4096 | Wv:4096 | Wo:4096
__global__ void cvt_all(const float* __restrict__ x,  const float* __restrict__ wq,
                        const float* __restrict__ wk, const float* __restrict__ wv,
                        const float* __restrict__ wo,
                        bf16* __restrict__ xb, bf16* __restrict__ wqkv,
                        bf16* __restrict__ wob) {
  int bid = blockIdx.x;
  const float* s; bf16* d; int base;
  if (bid < 8192)        { s = x;  d = xb;             base = bid; }
  else if (bid < 12288)  { s = wq; d = wqkv;           base = bid - 8192; }
  else if (bid < 16384)  { s = wk; d = wqkv + 4194304; base = bid - 12288; }
  else if (bid < 20480)  { s = wv; d = wqkv + 8388608; base = bid - 16384; }
  else                   { s = wo; d = wob;            base = bid - 20480; }
  int i = (base * 256 + threadIdx.x) * 4;
  float4 v = *(const float4*)(s + i);
  bf16x4 o = {(bf16)v.x, (bf16)v.y, (bf16)v.z, (bf16)v.w};
  *(bf16x4*)(d + i) = o;
}

// ---------------------------------------------------------------------------
// 16 MFMA cluster: one C-quadrant (4 M-frags x 2 N-frags, full K=64).
// All acc indices compile-time (rule #20).
template<int IB, int JB>
__device__ __forceinline__ void mfma_quad(f32x4 (&acc)[8][4],
                                          const bf16x8 (&a)[4][2],
                                          const bf16x8 (&b)[2][2]) {
#pragma unroll
  for (int i = 0; i < 4; ++i)
#pragma unroll
    for (int j = 0; j < 2; ++j) {
      acc[IB + i][JB + j] = __builtin_amdgcn_mfma_f32_16x16x32_bf16(
          a[i][0], b[j][0], acc[IB + i][JB + j], 0, 0, 0);
      acc[IB + i][JB + j] = __builtin_amdgcn_mfma_f32_16x16x32_bf16(
          a[i][1], b[j][1], acc[IB + i][JB + j], 0, 0, 0);
    }
}

#define SBAR()  __builtin_amdgcn_s_barrier()
#define LGKM0() asm volatile("s_waitcnt lgkmcnt(0)" ::: "memory")
#define VMC8()  asm volatile("s_waitcnt vmcnt(8)" ::: "memory")

// ---------------------------------------------------------------------------
// GEMM1 (8-phase 256x256, T2 swizzle + T4 DEEP counted vmcnt + T5 setprio):
// qkv = x(4096x2048) * Wqkv^T (6144x2048), RoPE fused for Q,K columns.
// 512 threads = 8 waves (2M x 4N), per-wave 128x64 output.
// LDS 128 KiB: 2 K-tile buffers. DEEP LEDGER (round-2 fix): during tile t's
// phases, stage tile t+2 into buf(t) regions as their reads retire:
//   P2 -> A chunks {0,2}  (freed by P1's a0 reads)
//   P3 -> B chunks {0,1,2} (all B freed by P2's b1 reads)
//   P4 -> B chunk 3, A chunks {1,3} (freed by P3's a1 reads)
// One wait/tile: vmcnt(8) at P4 — the 8 outstanding loads are tile t+2's, so
// tile t+1 (issued during t-1, 4-6 phases ago) is guaranteed landed.
// Swizzle: linear LDS dest (gload_lds constraint), global SOURCE column
// XOR-permuted by (tid&7)^(row&7); fragment reads re-apply the same XOR.
// Round-2 verified: conflicts 0, correctness pass (absmax 2.4e-4).
__global__ __launch_bounds__(512, 2) void gemm_qkv(
    const bf16* __restrict__ A, const bf16* __restrict__ Bm,
    const float* __restrict__ rc, const float* __restrict__ rs,
    bf16* __restrict__ C) {
  __shared__ alignas(16) bf16 As[2 * 256 * 64];   // 64 KB
  __shared__ alignas(16) bf16 Bs[2 * 256 * 64];   // 64 KB
  const int tid  = threadIdx.x;
  const int lane = tid & 63;
  const int wid  = tid >> 6;
  const int wr   = wid >> 2, wc = wid & 3;        // 2 x 4 wave grid
  const int quad = lane >> 4, c16 = lane & 15;
  const int m0 = blockIdx.y * 256, n0 = blockIdx.x * 256;

  // ---- staging addresses: linear LDS dest, inverse-swizzled global src ----
  const int trow = tid >> 3;                       // 0..63 (row within 64-row chunk)
  const int tcol = ((tid & 7) ^ (trow & 7)) * 8;   // swizzled source col (elems)
  const bf16* agS = A  + (size_t)(m0 + trow) * D_ + tcol;
  const bf16* bgS = Bm + (size_t)(n0 + trow) * D_ + tcol;
  char* asD = (char*)As + tid * 16;
  char* bsD = (char*)Bs + tid * 16;

  // ---- fragment-read bases (same XOR on the read side) ----
  const int xorv  = (c16 & 7) << 4;
  const int colh0 = (quad * 16) ^ xorv;            // k-half 0 column byte
  const char* aL = (const char*)As + (wr * 128 + c16) * 128 + colh0;
  const char* aH = (const char*)As + (wr * 128 + c16) * 128 + (colh0 ^ 64);
  const char* bL = (const char*)Bs + (wc * 64 + c16) * 128 + colh0;
  const char* bH = (const char*)Bs + (wc * 64 + c16) * 128 + (colh0 ^ 64);

  f32x4 acc[8][4] = {};

  // ---- prologue: tile0 -> buf0 (8 loads), tile1 -> buf1 (8 loads);
  //      vmcnt(8): tile0 landed, tile1 stays in flight across the barrier ----
  async16(agS,                 asD);
  async16(agS +  64 * D_,      asD + 8192);
  async16(agS + 128 * D_,      asD + 16384);
  async16(agS + 192 * D_,      asD + 24576);
  async16(bgS,                 bsD);
  async16(bgS +  64 * D_,      bsD + 8192);
  async16(bgS + 128 * D_,      bsD + 16384);
  async16(bgS + 192 * D_,      bsD + 24576);
  async16(agS + 64,            asD + 32768);
  async16(agS +  64 * D_ + 64, asD + 32768 + 8192);
  async16(agS + 128 * D_ + 64, asD + 32768 + 16384);
  async16(agS + 192 * D_ + 64, asD + 32768 + 24576);
  async16(bgS + 64,            bsD + 32768);
  async16(bgS +  64 * D_ + 64, bsD + 32768 + 8192);
  async16(bgS + 128 * D_ + 64, bsD + 32768 + 16384);
  async16(bgS + 192 * D_ + 64, bsD + 32768 + 24576);
  VMC8();
  SBAR();

  for (int t = 0; t < 32; ++t) {
    const int cb = (t & 1) << 15;                  // current buffer byte offset
    const int k2 = (t < 30) ? (t + 2) * 64 : 0;    // clamped (garbage unread)
    bf16x8 a0[4][2], a1[4][2], b0[2][2], b1[2][2];

    // ---- P1: read a0 + b0 (12 ds_reads); no staging (nothing freed) ----
#pragma unroll
    for (int i = 0; i < 4; ++i) {
      a0[i][0] = *(const bf16x8*)(aL + cb + i * 2048);
      a0[i][1] = *(const bf16x8*)(aH + cb + i * 2048);
    }
#pragma unroll
    for (int j = 0; j < 2; ++j) {
      b0[j][0] = *(const bf16x8*)(bL + cb + j * 2048);
      b0[j][1] = *(const bf16x8*)(bH + cb + j * 2048);
    }
    SBAR(); LGKM0();
    __builtin_amdgcn_s_setprio(1);
    mfma_quad<0, 0>(acc, a0, b0);
    __builtin_amdgcn_s_setprio(0);
    SBAR();

    // ---- P2: read b1; stage t+2 A-chunks {0,2} -> cb (freed at P1) ----
#pragma unroll
    for (int j = 0; j < 2; ++j) {
      b1[j][0] = *(const bf16x8*)(bL + cb + (2 + j) * 2048);
      b1[j][1] = *(const bf16x8*)(bH + cb + (2 + j) * 2048);
    }
    async16(agS + k2,            asD + cb);
    async16(agS + 128 * D_ + k2, asD + cb + 16384);
    SBAR(); LGKM0();
    __builtin_amdgcn_s_setprio(1);
    mfma_quad<0, 2>(acc, a0, b1);
    __builtin_amdgcn_s_setprio(0);
    SBAR();

    // ---- P3: read a1; stage t+2 B-chunks {0,1,2} -> cb (freed at P2) ----
#pragma unroll
    for (int i = 0; i < 4; ++i) {
      a1[i][0] = *(const bf16x8*)(aL + cb + (4 + i) * 2048);
      a1[i][1] = *(const bf16x8*)(aH + cb + (4 + i) * 2048);
    }
    async16(bgS + k2,            bsD + cb);
    async16(bgS +  64 * D_ + k2, bsD + cb + 8192);
    async16(bgS + 128 * D_ + k2, bsD + cb + 16384);
    SBAR(); LGKM0();
    __builtin_amdgcn_s_setprio(1);
    mfma_quad<4, 0>(acc, a1, b0);
    __builtin_amdgcn_s_setprio(0);
    SBAR();

    // ---- P4: stage t+2 B-chunk 3 + A-chunks {1,3} -> cb (freed at P3);
    //      DEEP wait: vmcnt(8) -> tile t+1 landed, t+2's 8 stay in flight ----
    async16(bgS + 192 * D_ + k2, bsD + cb + 24576);
    async16(agS +  64 * D_ + k2, asD + cb + 8192);
    async16(agS + 192 * D_ + k2, asD + cb + 24576);
    VMC8();
    SBAR();
    __builtin_amdgcn_s_setprio(1);
    mfma_quad<4, 2>(acc, a1, b1);
    __builtin_amdgcn_s_setprio(0);
    SBAR();
  }

  // ---- epilogue (n0 block-uniform: Q / K get RoPE, V passes through) ----
  if (n0 < 4096) {
    const float sc = (n0 < 2048) ? kQScale : 1.0f;
#pragma unroll
    for (int i = 0; i < 8; ++i) {
      const int gmi = m0 + wr * 128 + i * 16 + quad * 4;
#pragma unroll
      for (int j = 0; j < 4; ++j) {
        const int gn = n0 + wc * 64 + j * 16 + c16;
        const int d = gn & 127;
#pragma unroll
        for (int r = 0; r < 4; ++r) {
          float v = acc[i][j][r];
          float p = __shfl_xor(v, 1);          // partner (odd<->even d)
          const int gm = gmi + r;
          const int s = gm & 2047;
          const int si = s * 64 + (d >> 1);
          float cz = rc[si], sn = rs[si];
          float re = (v * cz - p * sn) * sc;   // valid on even lanes
          float im = (v * sn + p * cz) * sc;
          if (!(lane & 1)) {
            bf16x2 o = {(bf16)re, (bf16)im};
            *(bf16x2*)(C + (size_t)gm * NQKV + gn) = o;
          }
        }
      }
    }
  } else {
#pragma unroll
    for (int i = 0; i < 8; ++i) {
      const int gmi = m0 + wr * 128 + i * 16 + quad * 4;
#pragma unroll
      for (int j = 0; j < 4; ++j) {
        const int gn = n0 + wc * 64 + j * 16 + c16;
#pragma unroll
        for (int r = 0; r < 4; ++r) {
          float v = acc[i][j][r];
          float p = __shfl_xor(v, 1);
          if (!(lane & 1)) {
            bf16x2 o = {(bf16)v, (bf16)p};
            *(bf16x2*)(C + (size_t)(gmi + r) * NQKV + gn) = o;
          }
        }
      }
    }
  }
}

// ---------------------------------------------------------------------------
// Fused per-(b,h) score + weight + V-scale kernel:
//   lse2[s] = log2 sum_k 2^(q'_s . k_k), diag2[s] = q'_s . k_s  (LDS only)
//   t[b,s,h*128+d] = 2^(diag2-lse2) * V[b,s,h*128+d]
// Q,K,V read strided from unified qkv (row stride NQKV). Diag extraction
// uses STATIC acc indices only (R3 lesson: dynamic index -> scratch spill).
__global__ __launch_bounds__(256, 2) void score_wv(
    const bf16* __restrict__ qkv, bf16* __restrict__ t) {
  __shared__ alignas(16) bf16 Qs[4 * 128 * 32];  // 32KB
  __shared__ alignas(16) bf16 Ks[4 * 128 * 32];  // 32KB
  __shared__ float diagL[128];
  __shared__ float lseL[128];
  const int tid = threadIdx.x;
  const int lane = tid & 63, wv = tid >> 6;
  const int quad = lane >> 4, c16 = lane & 15;
  const int wm = wv * 32;                 // each wave owns 32 distinct Q rows
  const int bh = blockIdx.y;
  const int b = bh >> 4, h = bh & 15;
  const int m0 = blockIdx.x * 128;

  // Q columns [h*128, h*128+128); K columns [2048+h*128, ...)
  const bf16* qg = qkv + (size_t)(b * 2048 + m0 + (tid >> 2)) * NQKV
                 + h * 128 + (tid & 3) * 8;
  char* ql = (char*)Qs + tid * 16;
#pragma unroll
  for (int kt = 0; kt < 4; ++kt) {
    async16(qg + kt * 32,                     ql + kt * 8192);
    async16(qg + kt * 32 + (size_t)64 * NQKV, ql + kt * 8192 + 4096);
  }

  const bf16* kg = qkv + (size_t)(b * 2048 + (tid >> 2)) * NQKV
                 + 2048 + h * 128 + (tid & 3) * 8;
  char* kl = (char*)Ks + tid * 16;

  float sums[8] = {0.f, 0.f, 0.f, 0.f, 0.f, 0.f, 0.f, 0.f};

  for (int n0 = 0; n0 < S_; n0 += 128) {
    __syncthreads();
#pragma unroll
    for (int kt = 0; kt < 4; ++kt) {
      async16(kg + (size_t)n0 * NQKV + kt * 32,        kl + kt * 8192);
      async16(kg + (size_t)(n0 + 64) * NQKV + kt * 32, kl + kt * 8192 + 4096);
    }
    __syncthreads();
    f32x4 acc[2][8] = {};
#pragma unroll
    for (int kt = 0; kt < 4; ++kt) {
      bf16x8 a[2], bb[8];
#pragma unroll
      for (int i = 0; i < 2; ++i)
        a[i] = *(const bf16x8*)(Qs + kt * 4096 + (wm + i * 16 + c16) * 32 + quad * 8);
#pragma unroll
      for (int j = 0; j < 8; ++j)
        bb[j] = *(const bf16x8*)(Ks + kt * 4096 + (j * 16 + c16) * 32 + quad * 8);
#pragma unroll
      for (int i = 0; i < 2; ++i)
#pragma unroll
        for (int j = 0; j < 8; ++j)
          acc[i][j] = __builtin_amdgcn_mfma_f32_16x16x32_bf16(a[i], bb[j], acc[i][j], 0, 0, 0);
    }
    // Diagonal tile only; compile-time acc indices, wave-uniform j guard.
    if (n0 == m0) {
#pragma unroll
      for (int i = 0; i < 2; ++i)
#pragma unroll
        for (int j = 0; j < 8; ++j)
          if (j == 2 * wv + i) {
#pragma unroll
            for (int r = 0; r < 4; ++r)
              if (c16 == quad * 4 + r)
                diagL[wm + i * 16 + quad * 4 + r] = acc[i][j][r];
          }
    }
#pragma unroll
    for (int i = 0; i < 2; ++i)
#pragma unroll
      for (int j = 0; j < 8; ++j)
#pragma unroll
        for (int r = 0; r < 4; ++r)
          sums[i * 4 + r] += EXP2F(acc[i][j][r]);
  }

#pragma unroll
  for (int tix = 0; tix < 8; ++tix) {
    float s = sums[tix];
    s += __shfl_xor(s, 1);
    s += __shfl_xor(s, 2);
    s += __shfl_xor(s, 4);
    s += __shfl_xor(s, 8);
    if (c16 == 0) {
      int i = tix >> 2, r = tix & 3;
      lseL[wm + i * 16 + quad * 4 + r] = LOG2F(s);
    }
  }

  // ---- fused V scale: t = 2^(diag - lse) * V for this block's 128 rows ----
  __syncthreads();                       // diagL/lseL visible
  const int row = tid >> 1, ch = tid & 1;
  const float w = EXP2F(diagL[row] - lseL[row]);
  const size_t grow = (size_t)(b * 2048 + m0 + row);
  const bf16* vsrc = qkv + grow * NQKV + 4096 + h * 128 + ch * 64;
  bf16* tdst = t + grow * 2048 + h * 128 + ch * 64;
#pragma unroll
  for (int c = 0; c < 8; ++c) {
    bf16x8 vv = *(const bf16x8*)(vsrc + c * 8);
    bf16x8 oo;
#pragma unroll
    for (int r = 0; r < 8; ++r) oo[r] = (bf16)((float)vv[r] * w);
    *(bf16x8*)(tdst + c * 8) = oo;
  }
}

// ---------------------------------------------------------------------------
// GEMM2: out(f32) = t(4096x2048 bf16) * Wo^T(2048x2048 bf16). BK=64, packed
// f32x2 stores via lane-pair shfl.
__global__ __launch_bounds__(256, 2) void gemm_out(
    const bf16* __restrict__ A, const bf16* __restrict__ Bm, float* __restrict__ C) {
  __shared__ alignas(16) bf16 As[2][128 * 32];
  __shared__ alignas(16) bf16 Bs[2][128 * 32];
  const int tid = threadIdx.x;
  const int lane = tid & 63, wv = tid >> 6;
  const int quad = lane >> 4, c16 = lane & 15;
  const int wm = (wv >> 1) * 64, wn = (wv & 1) * 64;
  const int m0 = blockIdx.y * 128, n0 = blockIdx.x * 128;

  const bf16* ag = A  + (size_t)(m0 + (tid >> 2)) * D_ + (tid & 3) * 8;
  const bf16* bg = Bm + (size_t)(n0 + (tid >> 2)) * D_ + (tid & 3) * 8;
  char* asl = (char*)As + tid * 16;
  char* bsl = (char*)Bs + tid * 16;

  f32x4 acc[4][4] = {};
  for (int k0 = 0; k0 < D_; k0 += 64) {
    __syncthreads();
    async16(ag + k0,                 asl);
    async16(ag + k0 + 64 * D_,       asl + 4096);
    async16(ag + k0 + 32,            asl + 8192);
    async16(ag + k0 + 32 + 64 * D_,  asl + 12288);
    async16(bg + k0,                 bsl);
    async16(bg + k0 + 64 * D_,       bsl + 4096);
    async16(bg + k0 + 32,            bsl + 8192);
    async16(bg + k0 + 32 + 64 * D_,  bsl + 12288);
    __syncthreads();
#pragma unroll
    for (int half = 0; half < 2; ++half) {
      bf16x8 af[4], bfr[4];
#pragma unroll
      for (int i = 0; i < 4; ++i)
        af[i] = *(const bf16x8*)(As[half] + (wm + i * 16 + c16) * 32 + quad * 8);
#pragma unroll
      for (int j = 0; j < 4; ++j)
        bfr[j] = *(const bf16x8*)(Bs[half] + (wn + j * 16 + c16) * 32 + quad * 8);
#pragma unroll
      for (int i = 0; i < 4; ++i)
#pragma unroll
        for (int j = 0; j < 4; ++j)
          acc[i][j] = __builtin_amdgcn_mfma_f32_16x16x32_bf16(af[i], bfr[j], acc[i][j], 0, 0, 0);
    }
  }
#pragma unroll
  for (int i = 0; i < 4; ++i)
#pragma unroll
    for (int j = 0; j < 4; ++j)
#pragma unroll
      for (int r = 0; r < 4; ++r) {
        float v = acc[i][j][r];
        float p = __shfl_xor(v, 1);
        if (!(lane & 1)) {
          int gm = m0 + wm + i * 16 + quad * 4 + r;
          int gn = n0 + wn + j * 16 + c16;
          float2 o = {v, p};
          *(float2*)(C + (size_t)gm * D_ + gn) = o;
        }
      }
}

// ---------------------------------------------------------------------------
extern "C" void kernel_launch(void* const* d_in, const int* in_sizes, int n_in,
                              void* d_out, int out_size, void* d_ws, size_t ws_size,
                              hipStream_t stream) {
  (void)in_sizes; (void)n_in; (void)out_size; (void)ws_size;
  const float* x  = (const float*)d_in[0];
  const float* rc = (const float*)d_in[1];
  const float* rs = (const float*)d_in[2];
  const float* Wq = (const float*)d_in[3];
  const float* Wk = (const float*)d_in[4];
  const float* Wv = (const float*)d_in[5];
  const float* Wo = (const float*)d_in[6];

  char* ws = (char*)d_ws;
  bf16* xb   = (bf16*)ws;                          // 16 MB slot (x bf16; reused as t)
  bf16* wqkv = (bf16*)(ws + 16777216);             // 24 MB (6144x2048)
  bf16* wob  = (bf16*)(ws + 16777216 + 25165824);  // 8 MB
  bf16* qkv  = (bf16*)(ws + 16777216 + 25165824 + 8388608);   // 48 MB (4096x6144)

  cvt_all<<<24576, 256, 0, stream>>>(x, Wq, Wk, Wv, Wo, xb, wqkv, wob);
  gemm_qkv<<<dim3(24, 16), 512, 0, stream>>>(xb, wqkv, rc, rs, qkv);
  score_wv<<<dim3(16, 32), 256, 0, stream>>>(qkv, xb /* t reuses xb */);
  gemm_out<<<dim3(16, 32), 256, 0, stream>>>(xb, wob, (float*)d_out);
}

// Round 4
// 379.582 us; speedup vs baseline: 1.1269x; 1.1269x over previous
//
#include <hip/hip_runtime.h>

// Problem constants: B=2, S=2048, D=2048, H=16, DH=128
#define B_  2
#define S_  2048
#define D_  2048
#define H_  16
#define DH_ 128
#define NQKV 6144              // Q|K|V concatenated column dim

typedef __bf16 bf16;
typedef __bf16 bf16x2 __attribute__((ext_vector_type(2)));
typedef __bf16 bf16x4 __attribute__((ext_vector_type(4)));
typedef __bf16 bf16x8 __attribute__((ext_vector_type(8)));
typedef float  f32x4  __attribute__((ext_vector_type(4)));

// 2^x and log2(x) via the raw ISA ops (v_exp_f32 / v_log_f32).
#define EXP2F(x) __builtin_amdgcn_exp2f(x)
#define LOG2F(x) __builtin_amdgcn_logf(x)

// DH^-0.5 * log2(e): fold softmax scale AND the exp->exp2 conversion into Q.
static constexpr float kQScale = 0.08838834764831845f * 1.4426950408889634f;

__device__ __forceinline__ void async16(const void* g, void* l) {
  __builtin_amdgcn_global_load_lds(
      (const __attribute__((address_space(1))) void*)g,
      (__attribute__((address_space(3))) void*)l, 16, 0, 0);
}

// ---------------------------------------------------------------------------
// Single fp32 -> bf16 conversion kernel for all 5 tensors (block-uniform
// region select; merging 5 dispatches -> 1 to cut launch overhead).
// Regions (blocks of 1024 elems): x:8192 | Wq:4096 | Wk:4096 | Wv:4096 | Wo:4096
__global__ void cvt_all(const float* __restrict__ x,  const float* __restrict__ wq,
                        const float* __restrict__ wk, const float* __restrict__ wv,
                        const float* __restrict__ wo,
                        bf16* __restrict__ xb, bf16* __restrict__ wqkv,
                        bf16* __restrict__ wob) {
  int bid = blockIdx.x;
  const float* s; bf16* d; int base;
  if (bid < 8192)        { s = x;  d = xb;             base = bid; }
  else if (bid < 12288)  { s = wq; d = wqkv;           base = bid - 8192; }
  else if (bid < 16384)  { s = wk; d = wqkv + 4194304; base = bid - 12288; }
  else if (bid < 20480)  { s = wv; d = wqkv + 8388608; base = bid - 16384; }
  else                   { s = wo; d = wob;            base = bid - 20480; }
  int i = (base * 256 + threadIdx.x) * 4;
  float4 v = *(const float4*)(s + i);
  bf16x4 o = {(bf16)v.x, (bf16)v.y, (bf16)v.z, (bf16)v.w};
  *(bf16x4*)(d + i) = o;
}

// ---------------------------------------------------------------------------
// GEMM1 (round-0 verified structure, 141.8 us measured): qkv = x(4096x2048) *
// Wqkv^T (6144x2048), RoPE fused for the Q,K column regions (f32 via lane-pair
// shfl), Q scaled by kQScale. Output row-major 4096x6144 bf16. BK=64 (two 32-K
// sub-tiles per barrier pair). NOTE: two 8-phase/256^2 rewrites (r2: 187us,
// r3: 223us) both measured WORSE than this 2-phase at 1 block/CU — reverted.
__global__ __launch_bounds__(256, 2) void gemm_qkv(
    const bf16* __restrict__ A, const bf16* __restrict__ Bm,
    const float* __restrict__ rc, const float* __restrict__ rs,
    bf16* __restrict__ C) {
  __shared__ alignas(16) bf16 As[2][128 * 32];   // 16 KB
  __shared__ alignas(16) bf16 Bs[2][128 * 32];   // 16 KB
  const int tid = threadIdx.x;
  const int lane = tid & 63;
  const int wv = tid >> 6;
  const int quad = lane >> 4, c16 = lane & 15;
  const int wm = (wv >> 1) * 64, wn = (wv & 1) * 64;
  const int m0 = blockIdx.y * 128, n0 = blockIdx.x * 128;

  const bf16* ag = A  + (size_t)(m0 + (tid >> 2)) * D_ + (tid & 3) * 8;
  const bf16* bg = Bm + (size_t)(n0 + (tid >> 2)) * D_ + (tid & 3) * 8;
  char* asl = (char*)As + tid * 16;
  char* bsl = (char*)Bs + tid * 16;

  f32x4 acc[4][4] = {};
  for (int k0 = 0; k0 < D_; k0 += 64) {
    __syncthreads();
    async16(ag + k0,                 asl);
    async16(ag + k0 + 64 * D_,       asl + 4096);
    async16(ag + k0 + 32,            asl + 8192);
    async16(ag + k0 + 32 + 64 * D_,  asl + 12288);
    async16(bg + k0,                 bsl);
    async16(bg + k0 + 64 * D_,       bsl + 4096);
    async16(bg + k0 + 32,            bsl + 8192);
    async16(bg + k0 + 32 + 64 * D_,  bsl + 12288);
    __syncthreads();
#pragma unroll
    for (int half = 0; half < 2; ++half) {
      bf16x8 af[4], bfr[4];
#pragma unroll
      for (int i = 0; i < 4; ++i)
        af[i] = *(const bf16x8*)(As[half] + (wm + i * 16 + c16) * 32 + quad * 8);
#pragma unroll
      for (int j = 0; j < 4; ++j)
        bfr[j] = *(const bf16x8*)(Bs[half] + (wn + j * 16 + c16) * 32 + quad * 8);
#pragma unroll
      for (int i = 0; i < 4; ++i)
#pragma unroll
        for (int j = 0; j < 4; ++j)
          acc[i][j] = __builtin_amdgcn_mfma_f32_16x16x32_bf16(af[i], bfr[j], acc[i][j], 0, 0, 0);
    }
  }

  // ---- epilogue (n0 block-uniform: Q / K get RoPE, V passes through) ----
  if (n0 < 4096) {
    const float sc = (n0 < 2048) ? kQScale : 1.0f;
#pragma unroll
    for (int i = 0; i < 4; ++i) {
      const int gmi = m0 + wm + i * 16 + quad * 4;
#pragma unroll
      for (int j = 0; j < 4; ++j) {
        const int gn = n0 + wn + j * 16 + c16;
        const int d = gn & 127;
#pragma unroll
        for (int r = 0; r < 4; ++r) {
          float v = acc[i][j][r];
          float p = __shfl_xor(v, 1);          // partner (odd<->even d)
          const int gm = gmi + r;
          const int s = gm & 2047;
          const int si = s * 64 + (d >> 1);
          float c = rc[si], sn = rs[si];
          float re = (v * c - p * sn) * sc;    // valid on even lanes
          float im = (v * sn + p * c) * sc;
          if (!(lane & 1)) {
            bf16x2 o = {(bf16)re, (bf16)im};
            *(bf16x2*)(C + (size_t)gm * NQKV + gn) = o;
          }
        }
      }
    }
  } else {
#pragma unroll
    for (int i = 0; i < 4; ++i) {
      const int gmi = m0 + wm + i * 16 + quad * 4;
#pragma unroll
      for (int j = 0; j < 4; ++j) {
        const int gn = n0 + wn + j * 16 + c16;
#pragma unroll
        for (int r = 0; r < 4; ++r) {
          float v = acc[i][j][r];
          float p = __shfl_xor(v, 1);
          if (!(lane & 1)) {
            bf16x2 o = {(bf16)v, (bf16)p};
            *(bf16x2*)(C + (size_t)(gmi + r) * NQKV + gn) = o;
          }
        }
      }
    }
  }
}

// ---------------------------------------------------------------------------
// Fused per-(b,h) score + weight + V-scale kernel (v2: 64-row K-chunks):
//   lse2[s] = log2 sum_k 2^(q'_s . k_k), diag2[s] = q'_s . k_s  (LDS only)
//   t[b,s,h*128+d] = 2^(diag2-lse2) * V[b,s,h*128+d]
// Round-4 change: K staged in 64-row chunks (Ks 32->16 KB) so LDS drops
// 65->49 KB -> 3 blocks/CU (was 2); acc[2][8]->acc[2][4] (-32 AGPRs). More
// TLP on a latency-bound loop. Diagonal: wave wv's diag chunk is
// n0 == m0 + (wv>>1)*64 with j == (wv&1)*2 + i (wave-uniform, static idx).
__global__ __launch_bounds__(256, 2) void score_wv(
    const bf16* __restrict__ qkv, bf16* __restrict__ t) {
  __shared__ alignas(16) bf16 Qs[4 * 128 * 32];  // 32KB
  __shared__ alignas(16) bf16 Ks[4 * 64 * 32];   // 16KB
  __shared__ float diagL[128];
  __shared__ float lseL[128];
  const int tid = threadIdx.x;
  const int lane = tid & 63, wv = tid >> 6;
  const int quad = lane >> 4, c16 = lane & 15;
  const int wm = wv * 32;                 // each wave owns 32 distinct Q rows
  const int bh = blockIdx.y;
  const int b = bh >> 4, h = bh & 15;
  const int m0 = blockIdx.x * 128;

  // Q columns [h*128, h*128+128); K columns [2048+h*128, ...)
  const bf16* qg = qkv + (size_t)(b * 2048 + m0 + (tid >> 2)) * NQKV
                 + h * 128 + (tid & 3) * 8;
  char* ql = (char*)Qs + tid * 16;
#pragma unroll
  for (int kt = 0; kt < 4; ++kt) {
    async16(qg + kt * 32,                     ql + kt * 8192);
    async16(qg + kt * 32 + (size_t)64 * NQKV, ql + kt * 8192 + 4096);
  }

  const bf16* kg = qkv + (size_t)(b * 2048 + (tid >> 2)) * NQKV
                 + 2048 + h * 128 + (tid & 3) * 8;
  char* kl = (char*)Ks + tid * 16;

  float sums[8] = {0.f, 0.f, 0.f, 0.f, 0.f, 0.f, 0.f, 0.f};
  const int diagChunk = m0 + ((wv >> 1) << 6);   // wave-uniform

  for (int n0 = 0; n0 < S_; n0 += 64) {
    __syncthreads();                             // prior reads of Ks/Qs done
#pragma unroll
    for (int kt = 0; kt < 4; ++kt)
      async16(kg + (size_t)n0 * NQKV + kt * 32, kl + kt * 4096);
    __syncthreads();                             // K chunk (and Q, iter 0) landed
    f32x4 acc[2][4] = {};
#pragma unroll
    for (int kt = 0; kt < 4; ++kt) {
      bf16x8 a[2], bb[4];
#pragma unroll
      for (int i = 0; i < 2; ++i)
        a[i] = *(const bf16x8*)(Qs + kt * 4096 + (wm + i * 16 + c16) * 32 + quad * 8);
#pragma unroll
      for (int j = 0; j < 4; ++j)
        bb[j] = *(const bf16x8*)(Ks + kt * 2048 + (j * 16 + c16) * 32 + quad * 8);
#pragma unroll
      for (int i = 0; i < 2; ++i)
#pragma unroll
        for (int j = 0; j < 4; ++j)
          acc[i][j] = __builtin_amdgcn_mfma_f32_16x16x32_bf16(a[i], bb[j], acc[i][j], 0, 0, 0);
    }
    // Diagonal chunk only; compile-time acc indices, wave-uniform j guard.
    if (n0 == diagChunk) {
#pragma unroll
      for (int i = 0; i < 2; ++i)
#pragma unroll
        for (int j = 0; j < 4; ++j)
          if (j == (wv & 1) * 2 + i) {
#pragma unroll
            for (int r = 0; r < 4; ++r)
              if (c16 == quad * 4 + r)
                diagL[wm + i * 16 + quad * 4 + r] = acc[i][j][r];
          }
    }
#pragma unroll
    for (int i = 0; i < 2; ++i)
#pragma unroll
      for (int j = 0; j < 4; ++j)
#pragma unroll
        for (int r = 0; r < 4; ++r)
          sums[i * 4 + r] += EXP2F(acc[i][j][r]);
  }

#pragma unroll
  for (int tix = 0; tix < 8; ++tix) {
    float s = sums[tix];
    s += __shfl_xor(s, 1);
    s += __shfl_xor(s, 2);
    s += __shfl_xor(s, 4);
    s += __shfl_xor(s, 8);
    if (c16 == 0) {
      int i = tix >> 2, r = tix & 3;
      lseL[wm + i * 16 + quad * 4 + r] = LOG2F(s);
    }
  }

  // ---- fused V scale: t = 2^(diag - lse) * V for this block's 128 rows ----
  __syncthreads();                       // diagL/lseL visible
  const int row = tid >> 1, ch = tid & 1;
  const float w = EXP2F(diagL[row] - lseL[row]);
  const size_t grow = (size_t)(b * 2048 + m0 + row);
  const bf16* vsrc = qkv + grow * NQKV + 4096 + h * 128 + ch * 64;
  bf16* tdst = t + grow * 2048 + h * 128 + ch * 64;
#pragma unroll
  for (int c = 0; c < 8; ++c) {
    bf16x8 vv = *(const bf16x8*)(vsrc + c * 8);
    bf16x8 oo;
#pragma unroll
    for (int r = 0; r < 8; ++r) oo[r] = (bf16)((float)vv[r] * w);
    *(bf16x8*)(tdst + c * 8) = oo;
  }
}

// ---------------------------------------------------------------------------
// GEMM2: out(f32) = t(4096x2048 bf16) * Wo^T(2048x2048 bf16). BK=64, packed
// f32x2 stores via lane-pair shfl. (round-0 verified structure)
__global__ __launch_bounds__(256, 2) void gemm_out(
    const bf16* __restrict__ A, const bf16* __restrict__ Bm, float* __restrict__ C) {
  __shared__ alignas(16) bf16 As[2][128 * 32];
  __shared__ alignas(16) bf16 Bs[2][128 * 32];
  const int tid = threadIdx.x;
  const int lane = tid & 63, wv = tid >> 6;
  const int quad = lane >> 4, c16 = lane & 15;
  const int wm = (wv >> 1) * 64, wn = (wv & 1) * 64;
  const int m0 = blockIdx.y * 128, n0 = blockIdx.x * 128;

  const bf16* ag = A  + (size_t)(m0 + (tid >> 2)) * D_ + (tid & 3) * 8;
  const bf16* bg = Bm + (size_t)(n0 + (tid >> 2)) * D_ + (tid & 3) * 8;
  char* asl = (char*)As + tid * 16;
  char* bsl = (char*)Bs + tid * 16;

  f32x4 acc[4][4] = {};
  for (int k0 = 0; k0 < D_; k0 += 64) {
    __syncthreads();
    async16(ag + k0,                 asl);
    async16(ag + k0 + 64 * D_,       asl + 4096);
    async16(ag + k0 + 32,            asl + 8192);
    async16(ag + k0 + 32 + 64 * D_,  asl + 12288);
    async16(bg + k0,                 bsl);
    async16(bg + k0 + 64 * D_,       bsl + 4096);
    async16(bg + k0 + 32,            bsl + 8192);
    async16(bg + k0 + 32 + 64 * D_,  bsl + 12288);
    __syncthreads();
#pragma unroll
    for (int half = 0; half < 2; ++half) {
      bf16x8 af[4], bfr[4];
#pragma unroll
      for (int i = 0; i < 4; ++i)
        af[i] = *(const bf16x8*)(As[half] + (wm + i * 16 + c16) * 32 + quad * 8);
#pragma unroll
      for (int j = 0; j < 4; ++j)
        bfr[j] = *(const bf16x8*)(Bs[half] + (wn + j * 16 + c16) * 32 + quad * 8);
#pragma unroll
      for (int i = 0; i < 4; ++i)
#pragma unroll
        for (int j = 0; j < 4; ++j)
          acc[i][j] = __builtin_amdgcn_mfma_f32_16x16x32_bf16(af[i], bfr[j], acc[i][j], 0, 0, 0);
    }
  }
#pragma unroll
  for (int i = 0; i < 4; ++i)
#pragma unroll
    for (int j = 0; j < 4; ++j)
#pragma unroll
      for (int r = 0; r < 4; ++r) {
        float v = acc[i][j][r];
        float p = __shfl_xor(v, 1);
        if (!(lane & 1)) {
          int gm = m0 + wm + i * 16 + quad * 4 + r;
          int gn = n0 + wn + j * 16 + c16;
          float2 o = {v, p};
          *(float2*)(C + (size_t)gm * D_ + gn) = o;
        }
      }
}

// ---------------------------------------------------------------------------
extern "C" void kernel_launch(void* const* d_in, const int* in_sizes, int n_in,
                              void* d_out, int out_size, void* d_ws, size_t ws_size,
                              hipStream_t stream) {
  (void)in_sizes; (void)n_in; (void)out_size; (void)ws_size;
  const float* x  = (const float*)d_in[0];
  const float* rc = (const float*)d_in[1];
  const float* rs = (const float*)d_in[2];
  const float* Wq = (const float*)d_in[3];
  const float* Wk = (const float*)d_in[4];
  const float* Wv = (const float*)d_in[5];
  const float* Wo = (const float*)d_in[6];

  char* ws = (char*)d_ws;
  bf16* xb   = (bf16*)ws;                          // 16 MB slot (x bf16; reused as t)
  bf16* wqkv = (bf16*)(ws + 16777216);             // 24 MB (6144x2048)
  bf16* wob  = (bf16*)(ws + 16777216 + 25165824);  // 8 MB
  bf16* qkv  = (bf16*)(ws + 16777216 + 25165824 + 8388608);   // 48 MB (4096x6144)

  cvt_all<<<24576, 256, 0, stream>>>(x, Wq, Wk, Wv, Wo, xb, wqkv, wob);
  gemm_qkv<<<dim3(48, 32), 256, 0, stream>>>(xb, wqkv, rc, rs, qkv);
  score_wv<<<dim3(16, 32), 256, 0, stream>>>(qkv, xb /* t reuses xb */);
  gemm_out<<<dim3(16, 32), 256, 0, stream>>>(xb, wob, (float*)d_out);
}